// Round 13
// baseline (1569.200 us; speedup 1.0000x reference)
//
#include <hip/hip_runtime.h>

#define Bv 2
#define Sv 2048
#define Dv 1024
#define Hv 16
#define HDv 64
#define FFv 4096
#define Vv 32000

typedef short bf16x8 __attribute__((ext_vector_type(8)));
typedef float f32x4 __attribute__((ext_vector_type(4)));
typedef unsigned short us8 __attribute__((ext_vector_type(8)));
typedef unsigned short us4 __attribute__((ext_vector_type(4)));
typedef unsigned short u16;

__device__ __forceinline__ u16 f2bf(float f) {
  union { float f; unsigned u; } x; x.f = f;
  x.u += 0x7fffu + ((x.u >> 16) & 1u);   // RNE
  return (u16)(x.u >> 16);
}
__device__ __forceinline__ u16 f2bf_rtz(float f) {
  union { float f; unsigned u; } x; x.f = f;
  return (u16)(x.u >> 16);
}

__device__ __forceinline__ void gld16(const void* g, void* l) {
  __builtin_amdgcn_global_load_lds(
      (const __attribute__((address_space(1))) unsigned*)g,
      (__attribute__((address_space(3))) unsigned*)l, 16, 0, 0);
}

// ---------------- embedding ----------------
__global__ __launch_bounds__(256) void k_embed(const int* __restrict__ tok,
    const float* __restrict__ te, const float* __restrict__ pe,
    float* __restrict__ h) {
  int row = blockIdx.x;
  int s = row & (Sv - 1);
  int t = tok[row];
  float4 va = ((const float4*)(te + (size_t)t * Dv))[threadIdx.x];
  float4 vb = ((const float4*)(pe + (size_t)s * Dv))[threadIdx.x];
  float4 o;
  o.x = va.x + vb.x; o.y = va.y + vb.y; o.z = va.z + vb.z; o.w = va.w + vb.w;
  ((float4*)(h + (size_t)row * Dv))[threadIdx.x] = o;
}

// ---------------- f32 -> bf16 convert ----------------
__global__ __launch_bounds__(256) void k_cvt(const float* __restrict__ x,
    u16* __restrict__ y, int n4) {
  int i = blockIdx.x * 256 + threadIdx.x;
  if (i >= n4) return;
  float4 v = ((const float4*)x)[i];
  us4 o = { f2bf(v.x), f2bf(v.y), f2bf(v.z), f2bf(v.w) };
  ((us4*)y)[i] = o;
}

// fused 3-source convert (QKV weights) -> contiguous [wq; wk; wv] bf16
__global__ __launch_bounds__(256) void k_cvt3(const float* __restrict__ a,
    const float* __restrict__ b, const float* __restrict__ c,
    u16* __restrict__ y, int n4each) {
  int i = blockIdx.x * 256 + threadIdx.x;
  int sel = i / n4each;
  int j = i - sel * n4each;
  const float* src = sel == 0 ? a : (sel == 1 ? b : c);
  float4 v = ((const float4*)src)[j];
  us4 o = { f2bf(v.x), f2bf(v.y), f2bf(v.z), f2bf(v.w) };
  ((us4*)y)[i] = o;
}

// ---------------- layernorm ----------------
__global__ __launch_bounds__(256) void k_ln(const float* __restrict__ x,
    const float* __restrict__ g, const float* __restrict__ bb,
    u16* __restrict__ y) {
  int row = blockIdx.x, t = threadIdx.x;
  float4 v = ((const float4*)(x + (size_t)row * Dv))[t];
  float s = v.x + v.y + v.z + v.w;
#pragma unroll
  for (int m = 32; m; m >>= 1) s += __shfl_xor(s, m, 64);
  __shared__ float red[4];
  if ((t & 63) == 0) red[t >> 6] = s;
  __syncthreads();
  float mean = (red[0] + red[1] + red[2] + red[3]) * (1.0f / Dv);
  __syncthreads();
  float dx = v.x - mean, dy = v.y - mean, dz = v.z - mean, dw = v.w - mean;
  float s2 = dx * dx + dy * dy + dz * dz + dw * dw;
#pragma unroll
  for (int m = 32; m; m >>= 1) s2 += __shfl_xor(s2, m, 64);
  if ((t & 63) == 0) red[t >> 6] = s2;
  __syncthreads();
  float var = (red[0] + red[1] + red[2] + red[3]) * (1.0f / Dv);
  float rstd = rsqrtf(var + 1e-5f);
  float4 gg = ((const float4*)g)[t];
  float4 be = ((const float4*)bb)[t];
  us4 o = { f2bf(dx * rstd * gg.x + be.x), f2bf(dy * rstd * gg.y + be.y),
            f2bf(dz * rstd * gg.z + be.z), f2bf(dw * rstd * gg.w + be.w) };
  ((us4*)(y + (size_t)row * Dv))[t] = o;
}

// ==== BK=32 swizzled-LDS helpers (64-B rows, 4 slots, phys = s ^ ((row>>1)&3)) ====
__device__ __forceinline__ void stage32(const u16* __restrict__ g, int ldK,
    u16* lds, int row_base, int kt, int lane) {
  int row = row_base + (lane >> 2);
  int slot = (lane & 3) ^ ((row >> 1) & 3);
  const u16* src = g + (size_t)row * ldK + (kt << 5) + (slot << 3);
  gld16(src, lds + (row_base << 5));   // wave-uniform base; HW adds lane*16B
}
__device__ __forceinline__ bf16x8 ldfragA(const u16* lds, int row, int ks) {
  return *(const bf16x8*)((const char*)lds + row * 64 + ((ks ^ ((row >> 1) & 3)) << 4));
}

// ------- 128x256 BK=32 BT GEMM: A via LDS (3-buffer), B DIRECT global->reg ----
// B-frags (2-way wave reuse only) are loaded per-lane from global (L1/L2-hit;
// uniform SGPR base + 32-bit voffset), pipelined 1 tile ahead into a ping-pong
// register pair (static indexing via 2x unroll). LDS traffic/CU-round drops
// 176KB -> 80KB (~312 cyc) ~= MFMA 310 cyc. vmcnt queue per tile (in-order):
// [bf_next x4, A-stage t+2] -> end-of-tile vmcnt(1) keeps only A-stage in
// flight; everything tile t+1 needs has landed. Never drains to 0 mid-loop.
#define TILE8(T, CUR, NXT, P)                                                \
  {                                                                          \
    if ((T) + 1 < NT) {                                                      \
      const u16* bp = Bgw + ((T) + 1) * 32;                                  \
      _Pragma("unroll")                                                      \
      for (int n = 0; n < 4; n++)                                            \
        NXT[n] = *(const bf16x8*)(bp + (size_t)n * 16 * K);                  \
    }                                                                        \
    if ((T) + 2 < NT)                                                        \
      stage32(Ag, K, As[(P) + 2 >= 3 ? (P) - 1 : (P) + 2], wid * 16,         \
              (T) + 2, lane);                                                \
    _Pragma("unroll")                                                        \
    for (int f = 0; f < 4; f++)                                              \
      af[f] = ldfragA(As[P], wr * 64 + f * 16 + frow, ks);                   \
    __builtin_amdgcn_s_setprio(1);                                           \
    _Pragma("unroll")                                                        \
    for (int f = 0; f < 4; f++)                                              \
      _Pragma("unroll")                                                      \
      for (int n = 0; n < 4; n++)                                            \
        acc[f][n] = __builtin_amdgcn_mfma_f32_16x16x32_bf16(af[f], CUR[n],   \
                                                            acc[f][n],0,0,0);\
    __builtin_amdgcn_s_setprio(0);                                           \
    __builtin_amdgcn_sched_barrier(0);                                       \
    if ((T) + 2 < NT) { asm volatile("s_waitcnt vmcnt(1)" ::: "memory"); }   \
    else              { asm volatile("s_waitcnt vmcnt(0)" ::: "memory"); }   \
    __builtin_amdgcn_s_barrier();                                            \
  }

template <int EPI>
__global__ __launch_bounds__(512, 4) void k_gemm8(const u16* __restrict__ A,
    const u16* __restrict__ Bm, const float* __restrict__ res,
    float* __restrict__ Cf, u16* __restrict__ Cb, int M, int N, int K) {
  __shared__ u16 As[3][128 * 32];   // 24 KiB total
  int TM = M >> 7, TN = N >> 8, nwg = TM * TN;
  int orig = blockIdx.x;
  int qd = nwg >> 3, rm = nwg & 7, xcd = orig & 7;
  int wg = (xcd < rm ? xcd * (qd + 1) : rm * (qd + 1) + (xcd - rm) * qd) + (orig >> 3);
  int bm = wg % TM, bn = wg / TM;   // M fastest: consecutive blocks share B panel
  int m0 = bm << 7, n0 = bn << 8;
  int lane = threadIdx.x & 63, wid = threadIdx.x >> 6;
  int wr = wid >> 2, wc = wid & 3;  // 2x4 waves, per-wave 64x64
  int NT = K >> 5;
  const u16* Ag = A + (size_t)m0 * K;
  int frow = lane & 15, ks = lane >> 4;
  // per-lane B base: row (wc*64 + frow), k-slot ks; frag n adds n*16*K
  const u16* Bgw = Bm + (size_t)n0 * K + (size_t)(wc * 64 + frow) * K + ks * 8;

  f32x4 acc[4][4] = {};
  bf16x8 af[4], bf0[4], bf1[4];

  // prologue: B tile0 -> bf0 (4 loads), stage A tiles 0,1 (2 loads)
#pragma unroll
  for (int n = 0; n < 4; n++) bf0[n] = *(const bf16x8*)(Bgw + (size_t)n * 16 * K);
  stage32(Ag, K, As[0], wid * 16, 0, lane);
  stage32(Ag, K, As[1], wid * 16, 1, lane);
  asm volatile("s_waitcnt vmcnt(1)" ::: "memory");   // bf0 + A0 done; A1 in flight
  __builtin_amdgcn_s_barrier();

  int p = 0;
  for (int t = 0; t < NT; t += 2) {
    TILE8(t, bf0, bf1, p);
    int p1 = p + 1 >= 3 ? 0 : p + 1;
    TILE8(t + 1, bf1, bf0, p1);
    p = p1 + 1 >= 3 ? 0 : p1 + 1;
  }

  // epilogue
#pragma unroll
  for (int f = 0; f < 4; f++) {
#pragma unroll
    for (int r = 0; r < 4; r++) {
      int row = m0 + wr * 64 + f * 16 + (lane >> 4) * 4 + r;
#pragma unroll
      for (int n = 0; n < 4; n++) {
        int col = n0 + wc * 64 + n * 16 + frow;
        float val = acc[f][n][r];
        size_t idx = (size_t)row * N + col;
        if constexpr (EPI == 1) { Cf[idx] = val + res[idx]; }
        else if constexpr (EPI == 0) { __builtin_nontemporal_store(val, &Cf[idx]); }
        else if constexpr (EPI == 2) { Cb[idx] = f2bf(val); }
        else { Cb[idx] = f2bf(fmaxf(val, 0.0f)); }
      }
    }
  }
}

// ------- 64x128 BK=32 BT GEMM: A via LDS (3-buffer), B direct global->reg ----
#define TILEN(T, CUR, NXT, P)                                                \
  {                                                                          \
    if ((T) + 1 < NT) {                                                      \
      const u16* bp = Bgw + ((T) + 1) * 32;                                  \
      _Pragma("unroll")                                                      \
      for (int n = 0; n < 4; n++)                                            \
        NXT[n] = *(const bf16x8*)(bp + (size_t)n * 16 * K);                  \
    }                                                                        \
    if ((T) + 2 < NT)                                                        \
      stage32(Ag, K, As[(P) + 2 >= 3 ? (P) - 1 : (P) + 2], wid * 16,         \
              (T) + 2, lane);                                                \
    _Pragma("unroll")                                                        \
    for (int f = 0; f < 2; f++)                                              \
      af[f] = ldfragA(As[P], wr * 32 + f * 16 + frow, ks);                   \
    __builtin_amdgcn_s_setprio(1);                                           \
    _Pragma("unroll")                                                        \
    for (int f = 0; f < 2; f++)                                              \
      _Pragma("unroll")                                                      \
      for (int n = 0; n < 4; n++)                                            \
        acc[f][n] = __builtin_amdgcn_mfma_f32_16x16x32_bf16(af[f], CUR[n],   \
                                                            acc[f][n],0,0,0);\
    __builtin_amdgcn_s_setprio(0);                                           \
    __builtin_amdgcn_sched_barrier(0);                                       \
    if ((T) + 2 < NT) { asm volatile("s_waitcnt vmcnt(1)" ::: "memory"); }   \
    else              { asm volatile("s_waitcnt vmcnt(0)" ::: "memory"); }   \
    __builtin_amdgcn_s_barrier();                                            \
  }

template <int EPI>
__global__ __launch_bounds__(256, 4) void k_gemmn(const u16* __restrict__ A,
    const u16* __restrict__ Bm, const float* __restrict__ res,
    float* __restrict__ Cf, u16* __restrict__ Cb, int M, int N, int K) {
  __shared__ u16 As[3][64 * 32];    // 12 KiB total
  int TM = M >> 6, TN = N >> 7, nwg = TM * TN;
  int orig = blockIdx.x;
  int qd = nwg >> 3, rm = nwg & 7, xcd = orig & 7;
  int wg = (xcd < rm ? xcd * (qd + 1) : rm * (qd + 1) + (xcd - rm) * qd) + (orig >> 3);
  int bm = wg % TM, bn = wg / TM;   // M fastest: consecutive blocks share B panel
  int m0 = bm << 6, n0 = bn << 7;
  int lane = threadIdx.x & 63, wid = threadIdx.x >> 6;
  int wr = wid >> 1, wc = wid & 1;  // 2x2 waves, per-wave 32x64
  int NT = K >> 5;
  const u16* Ag = A + (size_t)m0 * K;
  int frow = lane & 15, ks = lane >> 4;
  const u16* Bgw = Bm + (size_t)n0 * K + (size_t)(wc * 64 + frow) * K + ks * 8;

  f32x4 acc[2][4] = {};
  bf16x8 af[2], bf0[4], bf1[4];

#pragma unroll
  for (int n = 0; n < 4; n++) bf0[n] = *(const bf16x8*)(Bgw + (size_t)n * 16 * K);
  stage32(Ag, K, As[0], wid * 16, 0, lane);
  stage32(Ag, K, As[1], wid * 16, 1, lane);
  asm volatile("s_waitcnt vmcnt(1)" ::: "memory");
  __builtin_amdgcn_s_barrier();

  int p = 0;
  for (int t = 0; t < NT; t += 2) {
    TILEN(t, bf0, bf1, p);
    int p1 = p + 1 >= 3 ? 0 : p + 1;
    TILEN(t + 1, bf1, bf0, p1);
    p = p1 + 1 >= 3 ? 0 : p1 + 1;
  }

#pragma unroll
  for (int f = 0; f < 2; f++) {
#pragma unroll
    for (int r = 0; r < 4; r++) {
      int row = m0 + wr * 32 + f * 16 + (lane >> 4) * 4 + r;
#pragma unroll
      for (int n = 0; n < 4; n++) {
        int col = n0 + wc * 64 + n * 16 + frow;
        float val = acc[f][n][r];
        size_t idx = (size_t)row * N + col;
        if constexpr (EPI == 1) { Cf[idx] = val + res[idx]; }
        else if constexpr (EPI == 0) { __builtin_nontemporal_store(val, &Cf[idx]); }
        else if constexpr (EPI == 2) { Cb[idx] = f2bf(val); }
        else { Cb[idx] = f2bf(fmaxf(val, 0.0f)); }
      }
    }
  }
}

// ---------------- V transpose ----------------
__global__ __launch_bounds__(256) void k_transpose(const u16* __restrict__ v,
    u16* __restrict__ vt, int stride) {
  int st = blockIdx.x & 31;
  int bh = blockIdx.x >> 5;
  int b = bh >> 4, hh = bh & 15;
  __shared__ u16 tile[64][72];
  int t = threadIdx.x;
  int rr = t >> 3, cc = (t & 7) << 3;
#pragma unroll
  for (int it = 0; it < 2; it++) {
    int r = rr + it * 32;
    us8 val = *(const us8*)(v + (size_t)(b * Sv + st * 64 + r) * stride + hh * HDv + cc);
    *(us8*)&tile[r][cc] = val;
  }
  __syncthreads();
#pragma unroll
  for (int it = 0; it < 2; it++) {
    int d = rr + it * 32;
    us8 val;
#pragma unroll
    for (int j = 0; j < 8; j++) val[j] = tile[cc + j][d];
    *(us8*)(vt + ((size_t)bh * HDv + d) * Sv + st * 64 + cc) = val;
  }
}

// ---------------- causal flash attention (wave-block, LPT, split diag) -------
__global__ __launch_bounds__(64) void k_attn(const u16* __restrict__ qg,
    const u16* __restrict__ kg, const u16* __restrict__ vt,
    u16* __restrict__ og) {
  int bid = blockIdx.x;
  int qt = 15 - (bid >> 7);        // heavy q-tiles dispatched first
  int bh = (bid >> 2) & 31;
  int strip = bid & 3;
  int b = bh >> 4, hh = bh & 15;
  int lane = threadIdx.x;
  int q0 = qt * 128 + strip * 32;
  __shared__ u16 plds[32 * 40];
  const int QS = 3 * Dv;
  const float sc2 = 0.18033688f;   // 0.125 * log2(e): P = exp2(s * sc2)
  int qcol = lane & 15, g = lane >> 4;

  bf16x8 onesf;
#pragma unroll
  for (int j = 0; j < 8; j++) onesf[j] = (short)0x3F80;   // bf16 1.0

  bf16x8 qf[2][2];
#pragma unroll
  for (int fm = 0; fm < 2; fm++)
#pragma unroll
    for (int dh = 0; dh < 2; dh++)
      qf[fm][dh] = *(const bf16x8*)(qg + (size_t)(b * Sv + q0 + fm * 16 + qcol) * QS
                                    + hh * HDv + dh * 32 + g * 8);

  f32x4 oacc[2][4] = {};
  f32x4 sacc[2] = {};
  int nfull = q0 >> 5;

  for (int kt = 0; kt <= nfull; kt++) {
    int k0 = kt * 32;
    bool diag = (kt == nfull);
    bf16x8 kf[2][2];
#pragma unroll
    for (int kn = 0; kn < 2; kn++)
#pragma unroll
      for (int dh = 0; dh < 2; dh++)
        kf[kn][dh] = *(const bf16x8*)(kg + (size_t)(b * Sv + k0 + kn * 16 + qcol) * QS
                                      + hh * HDv + dh * 32 + g * 8);
    f32x4 sa[2][2] = {};
#pragma unroll
    for (int dh = 0; dh < 2; dh++)
#pragma unroll
      for (int fm = 0; fm < 2; fm++)
#pragma unroll
        for (int kn = 0; kn < 2; kn++)   // SWAPPED: A=K, B=Q
          sa[fm][kn] = __builtin_amdgcn_mfma_f32_16x16x32_bf16(kf[kn][dh], qf[fm][dh], sa[fm][kn], 0, 0, 0);

#pragma unroll
    for (int fm = 0; fm < 2; fm++) {
      int qrow = fm * 16 + qcol;       // local row within the 32-strip
      float pv[2][4];
#pragma unroll
      for (int kn = 0; kn < 2; kn++)
#pragma unroll
        for (int r = 0; r < 4; r++) {
          float e = exp2f(sa[fm][kn][r] * sc2);
          if (diag && (kn * 16 + g * 4 + r) > qrow) e = 0.0f;
          pv[kn][r] = e;
        }
#pragma unroll
      for (int kn = 0; kn < 2; kn++) {
        us4 pk = { f2bf_rtz(pv[kn][0]), f2bf_rtz(pv[kn][1]),
                   f2bf_rtz(pv[kn][2]), f2bf_rtz(pv[kn][3]) };
        *(us4*)(plds + (fm * 16 + qcol) * 40 + kn * 16 + g * 4) = pk;
      }
    }
    bf16x8 pf[2];
#pragma unroll
    for (int fm = 0; fm < 2; fm++)
      pf[fm] = *(const bf16x8*)(plds + (fm * 16 + qcol) * 40 + g * 8);
    bf16x8 vf[4];
#pragma unroll
    for (int dn = 0; dn < 4; dn++)
      vf[dn] = *(const bf16x8*)(vt + ((size_t)bh * HDv + dn * 16 + qcol) * Sv
                                + k0 + g * 8);
#pragma unroll
    for (int fm = 0; fm < 2; fm++) {
      sacc[fm] = __builtin_amdgcn_mfma_f32_16x16x32_bf16(pf[fm], onesf, sacc[fm], 0, 0, 0);
#pragma unroll
      for (int dn = 0; dn < 4; dn++)
        oacc[fm][dn] = __builtin_amdgcn_mfma_f32_16x16x32_bf16(pf[fm], vf[dn], oacc[fm][dn], 0, 0, 0);
    }
  }

#pragma unroll
  for (int fm = 0; fm < 2; fm++)
#pragma unroll
    for (int r = 0; r < 4; r++) {
      float li = 1.0f / sacc[fm][r];
      int row = q0 + fm * 16 + g * 4 + r;
#pragma unroll
      for (int dn = 0; dn < 4; dn++)
        og[(size_t)(b * Sv + row) * Dv + hh * HDv + dn * 16 + qcol] =
            f2bf(oacc[fm][dn][r] * li);
    }
}

extern "C" void kernel_launch(void* const* d_in, const int* in_sizes, int n_in,
                              void* d_out, int out_size, void* d_ws, size_t ws_size,
                              hipStream_t stream) {
  const int*   tok  = (const int*)d_in[0];
  const float* te   = (const float*)d_in[1];
  const float* pe   = (const float*)d_in[2];
  const float* wq   = (const float*)d_in[3];
  const float* wk   = (const float*)d_in[4];
  const float* wvv  = (const float*)d_in[5];
  const float* wo   = (const float*)d_in[6];
  const float* w1   = (const float*)d_in[7];
  const float* w2   = (const float*)d_in[8];
  const float* ln1g = (const float*)d_in[9];
  const float* ln1b = (const float*)d_in[10];
  const float* ln2g = (const float*)d_in[11];
  const float* ln2b = (const float*)d_in[12];
  const float* lnfg = (const float*)d_in[13];
  const float* lnfb = (const float*)d_in[14];
  const float* wout = (const float*)d_in[15];
  float* out = (float*)d_out;

  char* p = (char*)d_ws;
  float* h  = (float*)p; p += (size_t)4096 * 1024 * 4;
  u16* a    = (u16*)p;   p += (size_t)4096 * 1024 * 2;
  u16* qkv  = (u16*)p;   p += (size_t)4096 * 3072 * 2;
  u16* vt   = (u16*)p;   p += (size_t)32 * 64 * 2048 * 2;
  u16* o    = (u16*)p;   p += (size_t)4096 * 1024 * 2;
  u16* f1   = (u16*)p;   p += (size_t)4096 * 4096 * 2;
  u16* wb   = (u16*)p;   p += (size_t)32000 * 1024 * 2;

  const int M = Bv * Sv;  // 4096

  k_embed<<<M, 256, 0, stream>>>(tok, te, pe, h);
  for (int l = 0; l < 2; l++) {
    k_ln<<<M, 256, 0, stream>>>(h, ln1g + l * Dv, ln1b + l * Dv, a);
    k_cvt3<<<3072, 256, 0, stream>>>(wq + (size_t)l * Dv * Dv, wk + (size_t)l * Dv * Dv,
                                     wvv + (size_t)l * Dv * Dv, wb, (Dv * Dv) / 4);
    k_gemm8<2><<<32 * 12, 512, 0, stream>>>(a, wb, nullptr, nullptr, qkv, M, 3 * Dv, Dv);
    k_transpose<<<1024, 256, 0, stream>>>(qkv + 2 * Dv, vt, 3 * Dv);
    k_attn<<<2048, 64, 0, stream>>>(qkv, qkv + Dv, vt, o);
    k_cvt<<<1024, 256, 0, stream>>>(wo + (size_t)l * Dv * Dv, wb, (Dv * Dv) / 4);
    k_gemmn<1><<<64 * 8, 256, 0, stream>>>(o, wb, h, h, nullptr, M, Dv, Dv);
    k_ln<<<M, 256, 0, stream>>>(h, ln2g + l * Dv, ln2b + l * Dv, a);
    k_cvt<<<4096, 256, 0, stream>>>(w1 + (size_t)l * FFv * Dv, wb, (FFv * Dv) / 4);
    k_gemm8<3><<<32 * 16, 512, 0, stream>>>(a, wb, nullptr, nullptr, f1, M, FFv, Dv);
    k_cvt<<<4096, 256, 0, stream>>>(w2 + (size_t)l * Dv * FFv, wb, (Dv * FFv) / 4);
    k_gemmn<1><<<64 * 8, 256, 0, stream>>>(f1, wb, h, h, nullptr, M, Dv, FFv);
  }
  k_ln<<<M, 256, 0, stream>>>(h, lnfg, lnfb, a);
  k_cvt<<<32000, 256, 0, stream>>>(wout, wb, (Vv * Dv) / 4);
  k_gemm8<0><<<32 * 125, 512, 0, stream>>>(a, wb, nullptr, out, nullptr, M, Vv, Dv);
}

// Round 15
// 918.048 us; speedup vs baseline: 1.7093x; 1.7093x over previous
//
#include <hip/hip_runtime.h>

#define Bv 2
#define Sv 2048
#define Dv 1024
#define Hv 16
#define HDv 64
#define FFv 4096
#define Vv 32000

typedef short bf16x8 __attribute__((ext_vector_type(8)));
typedef float f32x4 __attribute__((ext_vector_type(4)));
typedef unsigned short us8 __attribute__((ext_vector_type(8)));
typedef unsigned short us4 __attribute__((ext_vector_type(4)));
typedef unsigned short u16;

__device__ __forceinline__ u16 f2bf(float f) {
  union { float f; unsigned u; } x; x.f = f;
  x.u += 0x7fffu + ((x.u >> 16) & 1u);   // RNE
  return (u16)(x.u >> 16);
}
__device__ __forceinline__ u16 f2bf_rtz(float f) {
  union { float f; unsigned u; } x; x.f = f;
  return (u16)(x.u >> 16);
}

__device__ __forceinline__ void gld16(const void* g, void* l) {
  __builtin_amdgcn_global_load_lds(
      (const __attribute__((address_space(1))) unsigned*)g,
      (__attribute__((address_space(3))) unsigned*)l, 16, 0, 0);
}

// ---------------- embedding ----------------
__global__ __launch_bounds__(256) void k_embed(const int* __restrict__ tok,
    const float* __restrict__ te, const float* __restrict__ pe,
    float* __restrict__ h) {
  int row = blockIdx.x;
  int s = row & (Sv - 1);
  int t = tok[row];
  float4 va = ((const float4*)(te + (size_t)t * Dv))[threadIdx.x];
  float4 vb = ((const float4*)(pe + (size_t)s * Dv))[threadIdx.x];
  float4 o;
  o.x = va.x + vb.x; o.y = va.y + vb.y; o.z = va.z + vb.z; o.w = va.w + vb.w;
  ((float4*)(h + (size_t)row * Dv))[threadIdx.x] = o;
}

// ---------------- f32 -> bf16 convert (nontemporal f32 reads) ----------------
__global__ __launch_bounds__(256) void k_cvt(const float* __restrict__ x,
    u16* __restrict__ y, int n4) {
  int i = blockIdx.x * 256 + threadIdx.x;
  if (i >= n4) return;
  f32x4 v = __builtin_nontemporal_load(&((const f32x4*)x)[i]);
  us4 o = { f2bf(v.x), f2bf(v.y), f2bf(v.z), f2bf(v.w) };
  ((us4*)y)[i] = o;
}

// fused 3-source convert (QKV weights) -> contiguous [wq; wk; wv] bf16
__global__ __launch_bounds__(256) void k_cvt3(const float* __restrict__ a,
    const float* __restrict__ b, const float* __restrict__ c,
    u16* __restrict__ y, int n4each) {
  int i = blockIdx.x * 256 + threadIdx.x;
  int sel = i / n4each;
  int j = i - sel * n4each;
  const float* src = sel == 0 ? a : (sel == 1 ? b : c);
  f32x4 v = __builtin_nontemporal_load(&((const f32x4*)src)[j]);
  us4 o = { f2bf(v.x), f2bf(v.y), f2bf(v.z), f2bf(v.w) };
  ((us4*)y)[i] = o;
}

// ---------------- layernorm ----------------
__global__ __launch_bounds__(256) void k_ln(const float* __restrict__ x,
    const float* __restrict__ g, const float* __restrict__ bb,
    u16* __restrict__ y) {
  int row = blockIdx.x, t = threadIdx.x;
  float4 v = ((const float4*)(x + (size_t)row * Dv))[t];
  float s = v.x + v.y + v.z + v.w;
#pragma unroll
  for (int m = 32; m; m >>= 1) s += __shfl_xor(s, m, 64);
  __shared__ float red[4];
  if ((t & 63) == 0) red[t >> 6] = s;
  __syncthreads();
  float mean = (red[0] + red[1] + red[2] + red[3]) * (1.0f / Dv);
  __syncthreads();
  float dx = v.x - mean, dy = v.y - mean, dz = v.z - mean, dw = v.w - mean;
  float s2 = dx * dx + dy * dy + dz * dz + dw * dw;
#pragma unroll
  for (int m = 32; m; m >>= 1) s2 += __shfl_xor(s2, m, 64);
  if ((t & 63) == 0) red[t >> 6] = s2;
  __syncthreads();
  float var = (red[0] + red[1] + red[2] + red[3]) * (1.0f / Dv);
  float rstd = rsqrtf(var + 1e-5f);
  float4 gg = ((const float4*)g)[t];
  float4 be = ((const float4*)bb)[t];
  us4 o = { f2bf(dx * rstd * gg.x + be.x), f2bf(dy * rstd * gg.y + be.y),
            f2bf(dz * rstd * gg.z + be.z), f2bf(dw * rstd * gg.w + be.w) };
  ((us4*)(y + (size_t)row * Dv))[t] = o;
}

// ==== BK=32 swizzled-LDS helpers (64-B rows, 4 slots, phys = s ^ ((row>>1)&3)) ====
__device__ __forceinline__ void stage32(const u16* __restrict__ g, int ldK,
    u16* lds, int row_base, int kt, int lane) {
  int row = row_base + (lane >> 2);
  int slot = (lane & 3) ^ ((row >> 1) & 3);
  const u16* src = g + (size_t)row * ldK + (kt << 5) + (slot << 3);
  gld16(src, lds + (row_base << 5));   // wave-uniform base; HW adds lane*16B
}
__device__ __forceinline__ bf16x8 ldfragA(const u16* lds, int row, int ks) {
  return *(const bf16x8*)((const char*)lds + row * 64 + ((ks ^ ((row >> 1) & 3)) << 4));
}

// ------- 128x256 BK=32 BT GEMM, 8 waves (2x4) of 64x64 acc, 3-buffer -------
// Best measured structure (R12): stage t+2 at tile start into buf[(t+2)%3]
// (readers finished at t-1, barrier-confirmed -> race-free), compiler-counted
// lgkm waits, one 16-MFMA setprio cluster, counted vmcnt(3), 1 barrier/tile.
template <int EPI>
__global__ __launch_bounds__(512, 4) void k_gemm8(const u16* __restrict__ A,
    const u16* __restrict__ Bm, const float* __restrict__ res,
    float* __restrict__ Cf, u16* __restrict__ Cb, int M, int N, int K) {
  __shared__ u16 As[3][128 * 32];   // 24 KiB
  __shared__ u16 Bs[3][256 * 32];   // 48 KiB -> 72 KiB, 2 blocks/CU
  int TM = M >> 7, TN = N >> 8, nwg = TM * TN;
  int orig = blockIdx.x;
  int qd = nwg >> 3, rm = nwg & 7, xcd = orig & 7;
  int wg = (xcd < rm ? xcd * (qd + 1) : rm * (qd + 1) + (xcd - rm) * qd) + (orig >> 3);
  int bm = wg % TM, bn = wg / TM;   // M fastest: consecutive blocks share B panel
  int m0 = bm << 7, n0 = bn << 8;
  int lane = threadIdx.x & 63, wid = threadIdx.x >> 6;
  int wr = wid >> 2, wc = wid & 3;  // 2x4 waves, per-wave 64x64
  int NT = K >> 5;
  const u16* Ag = A + (size_t)m0 * K;
  const u16* Bg = Bm + (size_t)n0 * K;
  int frow = lane & 15, ks = lane >> 4;

  f32x4 acc[4][4] = {};
  bf16x8 af[4], bf[4];

  // prologue: stage tiles 0,1 (3 loads/wave each)
#pragma unroll
  for (int tt = 0; tt < 2; tt++) {
    stage32(Ag, K, As[tt], wid * 16, tt, lane);
    stage32(Bg, K, Bs[tt], wid * 32, tt, lane);
    stage32(Bg, K, Bs[tt], wid * 32 + 16, tt, lane);
  }
  asm volatile("s_waitcnt vmcnt(3)" ::: "memory");   // tile 0 landed; tile 1 in flight
  __builtin_amdgcn_s_barrier();

  int p = 0;
  for (int t = 0; t < NT; t++) {
    int q = p + 2 >= 3 ? p - 1 : p + 2;
    if (t + 2 < NT) {
      stage32(Ag, K, As[q], wid * 16, t + 2, lane);
      stage32(Bg, K, Bs[q], wid * 32, t + 2, lane);
      stage32(Bg, K, Bs[q], wid * 32 + 16, t + 2, lane);
    }
    const u16* Ab = As[p];
    const u16* Bb = Bs[p];
#pragma unroll
    for (int f = 0; f < 4; f++) af[f] = ldfragA(Ab, wr * 64 + f * 16 + frow, ks);
#pragma unroll
    for (int n = 0; n < 4; n++) bf[n] = ldfragA(Bb, wc * 64 + n * 16 + frow, ks);
    // compiler inserts counted lgkmcnt(N) per MFMA; reads drain under MFMA
    __builtin_amdgcn_s_setprio(1);
#pragma unroll
    for (int f = 0; f < 4; f++)
#pragma unroll
      for (int n = 0; n < 4; n++)
        acc[f][n] = __builtin_amdgcn_mfma_f32_16x16x32_bf16(af[f], bf[n], acc[f][n], 0, 0, 0);
    __builtin_amdgcn_s_setprio(0);
    if (t + 2 < NT) { asm volatile("s_waitcnt vmcnt(3)" ::: "memory"); }
    else            { asm volatile("s_waitcnt vmcnt(0)" ::: "memory"); }
    __builtin_amdgcn_s_barrier();
    p = p + 1 >= 3 ? 0 : p + 1;
  }

  // epilogue
#pragma unroll
  for (int f = 0; f < 4; f++) {
#pragma unroll
    for (int r = 0; r < 4; r++) {
      int row = m0 + wr * 64 + f * 16 + (lane >> 4) * 4 + r;
#pragma unroll
      for (int n = 0; n < 4; n++) {
        int col = n0 + wc * 64 + n * 16 + frow;
        float val = acc[f][n][r];
        size_t idx = (size_t)row * N + col;
        if constexpr (EPI == 1) { Cf[idx] = val + res[idx]; }
        else if constexpr (EPI == 0) { __builtin_nontemporal_store(val, &Cf[idx]); }
        else if constexpr (EPI == 2) { Cb[idx] = f2bf(val); }
        else { Cb[idx] = f2bf(fmaxf(val, 0.0f)); }
      }
    }
  }
}

// ------- 64x128 BK=32 BT GEMM, 4 waves (2x2) of 32x64 acc, 3-buffer -------
// N=1024 shapes (WO, FFN2): 512 blocks -> 2 blocks/CU fill.
template <int EPI>
__global__ __launch_bounds__(256, 4) void k_gemmn(const u16* __restrict__ A,
    const u16* __restrict__ Bm, const float* __restrict__ res,
    float* __restrict__ Cf, u16* __restrict__ Cb, int M, int N, int K) {
  __shared__ u16 As[3][64 * 32];    // 12 KiB
  __shared__ u16 Bs[3][128 * 32];   // 24 KiB -> 36 KiB
  int TM = M >> 6, TN = N >> 7, nwg = TM * TN;
  int orig = blockIdx.x;
  int qd = nwg >> 3, rm = nwg & 7, xcd = orig & 7;
  int wg = (xcd < rm ? xcd * (qd + 1) : rm * (qd + 1) + (xcd - rm) * qd) + (orig >> 3);
  int bm = wg % TM, bn = wg / TM;   // M fastest: consecutive blocks share B panel
  int m0 = bm << 6, n0 = bn << 7;
  int lane = threadIdx.x & 63, wid = threadIdx.x >> 6;
  int wr = wid >> 1, wc = wid & 1;  // 2x2 waves, per-wave 32x64
  int NT = K >> 5;
  const u16* Ag = A + (size_t)m0 * K;
  const u16* Bg = Bm + (size_t)n0 * K;
  int frow = lane & 15, ks = lane >> 4;

  f32x4 acc[2][4] = {};
  bf16x8 af[2], bf[4];

#pragma unroll
  for (int tt = 0; tt < 2; tt++) {
    stage32(Ag, K, As[tt], wid * 16, tt, lane);
    stage32(Bg, K, Bs[tt], wid * 32, tt, lane);
    stage32(Bg, K, Bs[tt], wid * 32 + 16, tt, lane);
  }
  asm volatile("s_waitcnt vmcnt(3)" ::: "memory");
  __builtin_amdgcn_s_barrier();

  int p = 0;
  for (int t = 0; t < NT; t++) {
    int q = p + 2 >= 3 ? p - 1 : p + 2;
    if (t + 2 < NT) {
      stage32(Ag, K, As[q], wid * 16, t + 2, lane);
      stage32(Bg, K, Bs[q], wid * 32, t + 2, lane);
      stage32(Bg, K, Bs[q], wid * 32 + 16, t + 2, lane);
    }
    const u16* Ab = As[p];
    const u16* Bb = Bs[p];
#pragma unroll
    for (int f = 0; f < 2; f++) af[f] = ldfragA(Ab, wr * 32 + f * 16 + frow, ks);
#pragma unroll
    for (int n = 0; n < 4; n++) bf[n] = ldfragA(Bb, wc * 64 + n * 16 + frow, ks);
    __builtin_amdgcn_s_setprio(1);
#pragma unroll
    for (int f = 0; f < 2; f++)
#pragma unroll
      for (int n = 0; n < 4; n++)
        acc[f][n] = __builtin_amdgcn_mfma_f32_16x16x32_bf16(af[f], bf[n], acc[f][n], 0, 0, 0);
    __builtin_amdgcn_s_setprio(0);
    if (t + 2 < NT) { asm volatile("s_waitcnt vmcnt(3)" ::: "memory"); }
    else            { asm volatile("s_waitcnt vmcnt(0)" ::: "memory"); }
    __builtin_amdgcn_s_barrier();
    p = p + 1 >= 3 ? 0 : p + 1;
  }

#pragma unroll
  for (int f = 0; f < 2; f++) {
#pragma unroll
    for (int r = 0; r < 4; r++) {
      int row = m0 + wr * 32 + f * 16 + (lane >> 4) * 4 + r;
#pragma unroll
      for (int n = 0; n < 4; n++) {
        int col = n0 + wc * 64 + n * 16 + frow;
        float val = acc[f][n][r];
        size_t idx = (size_t)row * N + col;
        if constexpr (EPI == 1) { Cf[idx] = val + res[idx]; }
        else if constexpr (EPI == 0) { __builtin_nontemporal_store(val, &Cf[idx]); }
        else if constexpr (EPI == 2) { Cb[idx] = f2bf(val); }
        else { Cb[idx] = f2bf(fmaxf(val, 0.0f)); }
      }
    }
  }
}

// ---------------- V transpose ----------------
__global__ __launch_bounds__(256) void k_transpose(const u16* __restrict__ v,
    u16* __restrict__ vt, int stride) {
  int st = blockIdx.x & 31;
  int bh = blockIdx.x >> 5;
  int b = bh >> 4, hh = bh & 15;
  __shared__ u16 tile[64][72];
  int t = threadIdx.x;
  int rr = t >> 3, cc = (t & 7) << 3;
#pragma unroll
  for (int it = 0; it < 2; it++) {
    int r = rr + it * 32;
    us8 val = *(const us8*)(v + (size_t)(b * Sv + st * 64 + r) * stride + hh * HDv + cc);
    *(us8*)&tile[r][cc] = val;
  }
  __syncthreads();
#pragma unroll
  for (int it = 0; it < 2; it++) {
    int d = rr + it * 32;
    us8 val;
#pragma unroll
    for (int j = 0; j < 8; j++) val[j] = tile[cc + j][d];
    *(us8*)(vt + ((size_t)bh * HDv + d) * Sv + st * 64 + cc) = val;
  }
}

// ---------------- causal flash attention (wave-block, LPT, split diag) -------
__global__ __launch_bounds__(64) void k_attn(const u16* __restrict__ qg,
    const u16* __restrict__ kg, const u16* __restrict__ vt,
    u16* __restrict__ og) {
  int bid = blockIdx.x;
  int qt = 15 - (bid >> 7);        // heavy q-tiles dispatched first
  int bh = (bid >> 2) & 31;
  int strip = bid & 3;
  int b = bh >> 4, hh = bh & 15;
  int lane = threadIdx.x;
  int q0 = qt * 128 + strip * 32;
  __shared__ u16 plds[32 * 40];
  const int QS = 3 * Dv;
  const float sc2 = 0.18033688f;   // 0.125 * log2(e): P = exp2(s * sc2)
  int qcol = lane & 15, g = lane >> 4;

  bf16x8 onesf;
#pragma unroll
  for (int j = 0; j < 8; j++) onesf[j] = (short)0x3F80;   // bf16 1.0

  bf16x8 qf[2][2];
#pragma unroll
  for (int fm = 0; fm < 2; fm++)
#pragma unroll
    for (int dh = 0; dh < 2; dh++)
      qf[fm][dh] = *(const bf16x8*)(qg + (size_t)(b * Sv + q0 + fm * 16 + qcol) * QS
                                    + hh * HDv + dh * 32 + g * 8);

  f32x4 oacc[2][4] = {};
  f32x4 sacc[2] = {};
  int nfull = q0 >> 5;

  for (int kt = 0; kt <= nfull; kt++) {
    int k0 = kt * 32;
    bool diag = (kt == nfull);
    bf16x8 kf[2][2];
#pragma unroll
    for (int kn = 0; kn < 2; kn++)
#pragma unroll
      for (int dh = 0; dh < 2; dh++)
        kf[kn][dh] = *(const bf16x8*)(kg + (size_t)(b * Sv + k0 + kn * 16 + qcol) * QS
                                      + hh * HDv + dh * 32 + g * 8);
    f32x4 sa[2][2] = {};
#pragma unroll
    for (int dh = 0; dh < 2; dh++)
#pragma unroll
      for (int fm = 0; fm < 2; fm++)
#pragma unroll
        for (int kn = 0; kn < 2; kn++)   // SWAPPED: A=K, B=Q
          sa[fm][kn] = __builtin_amdgcn_mfma_f32_16x16x32_bf16(kf[kn][dh], qf[fm][dh], sa[fm][kn], 0, 0, 0);

#pragma unroll
    for (int fm = 0; fm < 2; fm++) {
      int qrow = fm * 16 + qcol;       // local row within the 32-strip
      float pv[2][4];
#pragma unroll
      for (int kn = 0; kn < 2; kn++)
#pragma unroll
        for (int r = 0; r < 4; r++) {
          float e = exp2f(sa[fm][kn][r] * sc2);
          if (diag && (kn * 16 + g * 4 + r) > qrow) e = 0.0f;
          pv[kn][r] = e;
        }
#pragma unroll
      for (int kn = 0; kn < 2; kn++) {
        us4 pk = { f2bf_rtz(pv[kn][0]), f2bf_rtz(pv[kn][1]),
                   f2bf_rtz(pv[kn][2]), f2bf_rtz(pv[kn][3]) };
        *(us4*)(plds + (fm * 16 + qcol) * 40 + kn * 16 + g * 4) = pk;
      }
    }
    bf16x8 pf[2];
#pragma unroll
    for (int fm = 0; fm < 2; fm++)
      pf[fm] = *(const bf16x8*)(plds + (fm * 16 + qcol) * 40 + g * 8);
    bf16x8 vf[4];
#pragma unroll
    for (int dn = 0; dn < 4; dn++)
      vf[dn] = *(const bf16x8*)(vt + ((size_t)bh * HDv + dn * 16 + qcol) * Sv
                                + k0 + g * 8);
#pragma unroll
    for (int fm = 0; fm < 2; fm++) {
      sacc[fm] = __builtin_amdgcn_mfma_f32_16x16x32_bf16(pf[fm], onesf, sacc[fm], 0, 0, 0);
#pragma unroll
      for (int dn = 0; dn < 4; dn++)
        oacc[fm][dn] = __builtin_amdgcn_mfma_f32_16x16x32_bf16(pf[fm], vf[dn], oacc[fm][dn], 0, 0, 0);
    }
  }

#pragma unroll
  for (int fm = 0; fm < 2; fm++)
#pragma unroll
    for (int r = 0; r < 4; r++) {
      float li = 1.0f / sacc[fm][r];
      int row = q0 + fm * 16 + g * 4 + r;
#pragma unroll
      for (int dn = 0; dn < 4; dn++)
        og[(size_t)(b * Sv + row) * Dv + hh * HDv + dn * 16 + qcol] =
            f2bf(oacc[fm][dn][r] * li);
    }
}

extern "C" void kernel_launch(void* const* d_in, const int* in_sizes, int n_in,
                              void* d_out, int out_size, void* d_ws, size_t ws_size,
                              hipStream_t stream) {
  const int*   tok  = (const int*)d_in[0];
  const float* te   = (const float*)d_in[1];
  const float* pe   = (const float*)d_in[2];
  const float* wq   = (const float*)d_in[3];
  const float* wk   = (const float*)d_in[4];
  const float* wvv  = (const float*)d_in[5];
  const float* wo   = (const float*)d_in[6];
  const float* w1   = (const float*)d_in[7];
  const float* w2   = (const float*)d_in[8];
  const float* ln1g = (const float*)d_in[9];
  const float* ln1b = (const float*)d_in[10];
  const float* ln2g = (const float*)d_in[11];
  const float* ln2b = (const float*)d_in[12];
  const float* lnfg = (const float*)d_in[13];
  const float* lnfb = (const float*)d_in[14];
  const float* wout = (const float*)d_in[15];
  float* out = (float*)d_out;

  char* p = (char*)d_ws;
  float* h  = (float*)p; p += (size_t)4096 * 1024 * 4;
  u16* a    = (u16*)p;   p += (size_t)4096 * 1024 * 2;
  u16* qkv  = (u16*)p;   p += (size_t)4096 * 3072 * 2;
  u16* vt   = (u16*)p;   p += (size_t)32 * 64 * 2048 * 2;
  u16* o    = (u16*)p;   p += (size_t)4096 * 1024 * 2;
  u16* f1   = (u16*)p;   p += (size_t)4096 * 4096 * 2;
  u16* wb   = (u16*)p;   p += (size_t)32000 * 1024 * 2;

  const int M = Bv * Sv;  // 4096

  k_embed<<<M, 256, 0, stream>>>(tok, te, pe, h);
  for (int l = 0; l < 2; l++) {
    k_ln<<<M, 256, 0, stream>>>(h, ln1g + l * Dv, ln1b + l * Dv, a);
    k_cvt3<<<3072, 256, 0, stream>>>(wq + (size_t)l * Dv * Dv, wk + (size_t)l * Dv * Dv,
                                     wvv + (size_t)l * Dv * Dv, wb, (Dv * Dv) / 4);
    k_gemm8<2><<<32 * 12, 512, 0, stream>>>(a, wb, nullptr, nullptr, qkv, M, 3 * Dv, Dv);
    k_transpose<<<1024, 256, 0, stream>>>(qkv + 2 * Dv, vt, 3 * Dv);
    k_attn<<<2048, 64, 0, stream>>>(qkv, qkv + Dv, vt, o);
    k_cvt<<<1024, 256, 0, stream>>>(wo + (size_t)l * Dv * Dv, wb, (Dv * Dv) / 4);
    k_gemmn<1><<<64 * 8, 256, 0, stream>>>(o, wb, h, h, nullptr, M, Dv, Dv);
    k_ln<<<M, 256, 0, stream>>>(h, ln2g + l * Dv, ln2b + l * Dv, a);
    k_cvt<<<4096, 256, 0, stream>>>(w1 + (size_t)l * FFv * Dv, wb, (FFv * Dv) / 4);
    k_gemm8<3><<<32 * 16, 512, 0, stream>>>(a, wb, nullptr, nullptr, f1, M, FFv, Dv);
    k_cvt<<<4096, 256, 0, stream>>>(w2 + (size_t)l * Dv * FFv, wb, (Dv * FFv) / 4);
    k_gemmn<1><<<64 * 8, 256, 0, stream>>>(f1, wb, h, h, nullptr, M, Dv, FFv);
  }
  k_ln<<<M, 256, 0, stream>>>(h, lnfg, lnfb, a);
  k_cvt<<<32000, 256, 0, stream>>>(wout, wb, (Vv * Dv) / 4);
  k_gemm8<0><<<32 * 125, 512, 0, stream>>>(a, wb, nullptr, out, nullptr, M, Vv, Dv);
}